// Round 2
// baseline (154.081 us; speedup 1.0000x reference)
//
#include <hip/hip_runtime.h>

// SparseAttention: B=8, M=N=4096, K=64, R=128 nnz/row (uniform CSR).
// R3 was latency-bound on L2 gathers (66 GB/s/CU with only ~4 lines in
// flight/wave) + 3 barriers + wave0-only softmax.
// R4: one WAVE per row. 8 groups x 8 lanes, 16 edges/group -> 16-deep gather
//     streams, zero barriers, zero LDS (all reductions via shfl_xor butterflies),
//     fp16-staged Q, XCD-aware staging (data lands in the consuming XCD's L2),
//     nontemporal hints on streaming Q/cols/out, 1/den folded into epilogue.
// R4b: compile fix — __builtin_nontemporal_* requires clang ext-vector types,
//      not HIP_vector_type<float,4>; use native f32x4 typedef.
#define Bc 8
#define Mc 4096
#define Nc 4096
#define Kc 64
#define Rc 128

typedef _Float16 h16;
typedef h16 h16x2 __attribute__((ext_vector_type(2)));
typedef h16 h16x4 __attribute__((ext_vector_type(4)));
typedef h16 h16x8 __attribute__((ext_vector_type(8)));
typedef float f32x4 __attribute__((ext_vector_type(4)));

// fp32 -> fp16 staging for K, V, Q.  XCD-aware: batch b is converted by blocks
// with blockIdx&7 == b, so the staged bytes are written through (and stay
// dirty in) the same XCD L2 that sattn's gathers for batch b will read.
// Per XCD: K+V+Q fp16 = 1.5 MiB << 4 MiB L2.
__global__ __launch_bounds__(256) void cvt_fp16(
    const f32x4* __restrict__ K4, const f32x4* __restrict__ V4,
    const f32x4* __restrict__ Q4,
    h16x4* __restrict__ Kh4, h16x4* __restrict__ Vh4, h16x4* __restrict__ Qh4)
{
    const int nb4   = Nc * Kc / 4;          // 65536 f32x4 per tensor per batch
    const int b     = blockIdx.x & 7;       // XCD == batch
    const int chunk = blockIdx.x >> 3;      // 0..767
    const int tsel  = chunk >> 8;           // 0:K 1:V 2:Q (256 blocks each)
    const int idx   = b * nb4 + ((chunk & 255) << 8) + threadIdx.x;
    const f32x4* src = (tsel == 0) ? K4 : (tsel == 1) ? V4 : Q4;
    h16x4*       dst = (tsel == 0) ? Kh4 : (tsel == 1) ? Vh4 : Qh4;
    f32x4 v = __builtin_nontemporal_load(&src[idx]);
    h16x4 o = { (h16)v.x, (h16)v.y, (h16)v.z, (h16)v.w };
    dst[idx] = o;
}

__global__ __launch_bounds__(256, 4) void sattn_kernel(
    const int* __restrict__ cols,    // [M*R], sorted within row
    const h16* __restrict__ Qh,      // [B,M,K] fp16 (staged)
    const h16* __restrict__ Kh,      // [B,N,K] fp16 (staged)
    const h16* __restrict__ Vh,      // [B,N,K] fp16 (staged)
    float* __restrict__ out)         // [B,M,K] fp32
{
    const int b   = blockIdx.x & 7;            // XCD swizzle: one batch per XCD L2
    const int w   = threadIdx.x >> 6;          // wave 0..3: 4 independent rows/block
    const int row = ((blockIdx.x >> 3) << 2) | w;
    const int l   = threadIdx.x & 63;
    const int g   = l >> 3;                    // group 0..7
    const int ln  = l & 7;                     // lane-in-group; dims ln*8..ln*8+7

    const h16* Kb = Kh + ((size_t)b * Nc) * Kc;
    const h16* Vb = Vh + ((size_t)b * Nc) * Kc;

    // Q fragment (16 B), identical across the 8 groups -> L1 broadcast.
    h16x8 qv = __builtin_nontemporal_load(
        (const h16x8*)(Qh + (((size_t)b * Mc + row) << 6) + ln * 8));

    // Columns of this group's 16 edges: e = p*8 + g.  16 loads over the row's
    // 512 B col segment (L1-hot after first touch), independent chains.
    const int* crow = cols + row * Rc;
    int col16[16];
    #pragma unroll
    for (int p = 0; p < 16; ++p)
        col16[p] = __builtin_nontemporal_load(&crow[p * 8 + g]);

    // ---- SDDMM: 16-deep K-row gather (128 B rows; 8 lanes x 16 B, full lines) ----
    h16x8 kv[16];
    #pragma unroll
    for (int p = 0; p < 16; ++p)
        kv[p] = *(const h16x8*)(Kb + (((unsigned)col16[p]) << 6) + ln * 8);

    float lg[16];
    #pragma unroll
    for (int p = 0; p < 16; ++p) {
        float acc = 0.f;
        #pragma unroll
        for (int j = 0; j < 4; ++j) {
            h16x2 qj = { qv[2 * j], qv[2 * j + 1] };
            h16x2 kj = { kv[p][2 * j], kv[p][2 * j + 1] };
#if defined(__has_builtin)
#if __has_builtin(__builtin_amdgcn_fdot2)
            acc = __builtin_amdgcn_fdot2(qj, kj, acc, false);
#else
            acc += (float)qj.x * (float)kj.x + (float)qj.y * (float)kj.y;
#endif
#else
            acc += (float)qj.x * (float)kj.x + (float)qj.y * (float)kj.y;
#endif
        }
        // Reduce over the 8 lanes of the group; butterfly leaves the full dot
        // in every lane of the group.
        acc += __shfl_xor(acc, 1, 64);
        acc += __shfl_xor(acc, 2, 64);
        acc += __shfl_xor(acc, 4, 64);
        lg[p] = acc;                 // logit of edge p*8+g, all lanes of group g
    }

    // ---- V gathers: issue now; the softmax VALU below hides their latency ----
    h16x8 vv[16];
    #pragma unroll
    for (int p = 0; p < 16; ++p)
        vv[p] = *(const h16x8*)(Vb + (((unsigned)col16[p]) << 6) + ln * 8);

    // ---- softmax over the row's 128 logits, fully in-register ----
    float m = lg[0];
    #pragma unroll
    for (int p = 1; p < 16; ++p) m = fmaxf(m, lg[p]);
    m = fmaxf(m, __shfl_xor(m, 8, 64));
    m = fmaxf(m, __shfl_xor(m, 16, 64));
    m = fmaxf(m, __shfl_xor(m, 32, 64));

    float e[16];
    float s = 0.f;
    #pragma unroll
    for (int p = 0; p < 16; ++p) { e[p] = __expf(lg[p] - m); s += e[p]; }
    s += __shfl_xor(s, 8, 64);
    s += __shfl_xor(s, 16, 64);
    s += __shfl_xor(s, 32, 64);
    const float inv = 1.0f / s;      // applied once in the epilogue

    // ---- SPMM: acc8[j] = sum_e e_e * V[col_e][ln*8+j] over this group's edges ----
    float acc8[8] = {0.f, 0.f, 0.f, 0.f, 0.f, 0.f, 0.f, 0.f};
    #pragma unroll
    for (int p = 0; p < 16; ++p) {
        const float wp = e[p];
        #pragma unroll
        for (int j = 0; j < 8; ++j)
            acc8[j] = fmaf((float)vv[p][j], wp, acc8[j]);   // v_fma_mix
    }

    // ---- cross-group reduction in-register (butterfly over g) ----
    #pragma unroll
    for (int j = 0; j < 8; ++j) {
        acc8[j] += __shfl_xor(acc8[j], 8, 64);
        acc8[j] += __shfl_xor(acc8[j], 16, 64);
        acc8[j] += __shfl_xor(acc8[j], 32, 64);
    }

    if (g == 0) {
        float* orow = out + (((size_t)b * Mc + row) << 6) + ln * 8;
        f32x4 o0 = { acc8[0] * inv, acc8[1] * inv, acc8[2] * inv, acc8[3] * inv };
        f32x4 o1 = { acc8[4] * inv, acc8[5] * inv, acc8[6] * inv, acc8[7] * inv };
        __builtin_nontemporal_store(o0, (f32x4*)orow);
        __builtin_nontemporal_store(o1, (f32x4*)orow + 1);
    }
}

extern "C" void kernel_launch(void* const* d_in, const int* in_sizes, int n_in,
                              void* d_out, int out_size, void* d_ws, size_t ws_size,
                              hipStream_t stream) {
    // inputs: 0 row_indices, 1 row_offsets, 2 column_indices, 3 q3d, 4 k3d, 5 v3d, 6 values
    const int*   cols = (const int*)d_in[2];
    const float* Qm   = (const float*)d_in[3];
    const float* Km   = (const float*)d_in[4];
    const float* Vm   = (const float*)d_in[5];
    float* out = (float*)d_out;

    h16* Kh = (h16*)d_ws;
    h16* Vh = Kh + (size_t)Bc * Nc * Kc;
    h16* Qh = Vh + (size_t)Bc * Nc * Kc;   // 3 x 4.19 MB = 12.6 MB in d_ws

    cvt_fp16<<<dim3(Bc * 3 * 256), dim3(256), 0, stream>>>(
        (const f32x4*)Km, (const f32x4*)Vm, (const f32x4*)Qm,
        (h16x4*)Kh, (h16x4*)Vh, (h16x4*)Qh);

    sattn_kernel<<<dim3(Bc * Mc / 4), dim3(256), 0, stream>>>(cols, Qh, Kh, Vh, out);
}

// Round 3
// 144.707 us; speedup vs baseline: 1.0648x; 1.0648x over previous
//
#include <hip/hip_runtime.h>

// SparseAttention: B=8, M=N=4096, K=64, R=128 nnz/row (uniform CSR).
// Model (R3/R4 fit): random-gather is latency*MLP bound; throughput =
// lines_in_flight_per_CU * 128B / ~535cy.  R3: 23 waves x ~5 lines = 63us.
// R4: 10.5 waves x ~10 lines = 69us (deep streams worked, occupancy died).
// R5: 2 waves per row, 8 edges per lane-group -> ~75 VGPR keeps residency
//     high AND 8-deep gather streams; tiny-LDS (546B) cross-wave exchange;
//     16384 blocks for dispatch fill.  Target: ~20 waves x 8 lines.
#define Bc 8
#define Mc 4096
#define Nc 4096
#define Kc 64
#define Rc 128

typedef _Float16 h16;
typedef h16 h16x2 __attribute__((ext_vector_type(2)));
typedef h16 h16x4 __attribute__((ext_vector_type(4)));
typedef h16 h16x8 __attribute__((ext_vector_type(8)));
typedef float f32x4 __attribute__((ext_vector_type(4)));

// fp32 -> fp16 staging for K, V, Q.  XCD-aware: batch b converted by blocks
// with blockIdx&7 == b (same XCD that sattn's batch-b gathers run on).
__global__ __launch_bounds__(256) void cvt_fp16(
    const f32x4* __restrict__ K4, const f32x4* __restrict__ V4,
    const f32x4* __restrict__ Q4,
    h16x4* __restrict__ Kh4, h16x4* __restrict__ Vh4, h16x4* __restrict__ Qh4)
{
    const int nb4   = Nc * Kc / 4;          // 65536 f32x4 per tensor per batch
    const int b     = blockIdx.x & 7;       // XCD == batch
    const int chunk = blockIdx.x >> 3;      // 0..767
    const int tsel  = chunk >> 8;           // 0:K 1:V 2:Q (256 blocks each)
    const int idx   = b * nb4 + ((chunk & 255) << 8) + threadIdx.x;
    const f32x4* src = (tsel == 0) ? K4 : (tsel == 1) ? V4 : Q4;
    h16x4*       dst = (tsel == 0) ? Kh4 : (tsel == 1) ? Vh4 : Qh4;
    f32x4 v = __builtin_nontemporal_load(&src[idx]);
    h16x4 o = { (h16)v.x, (h16)v.y, (h16)v.z, (h16)v.w };
    dst[idx] = o;
}

__global__ __launch_bounds__(256, 6) void sattn_kernel(
    const int* __restrict__ cols,    // [M*R], sorted within row
    const h16* __restrict__ Qh,      // [B,M,K] fp16 (staged)
    const h16* __restrict__ Kh,      // [B,N,K] fp16 (staged)
    const h16* __restrict__ Vh,      // [B,N,K] fp16 (staged)
    float* __restrict__ out)         // [B,M,K] fp32
{
    const int b    = blockIdx.x & 7;          // XCD swizzle: one batch per XCD L2
    const int rb   = blockIdx.x >> 3;         // row-pair index within batch
    const int w    = threadIdx.x >> 6;        // wave 0..3
    const int rw   = w >> 1;                  // row-in-block 0/1
    const int half = w & 1;                   // which 64 of the row's 128 edges
    const int row  = rb * 2 + rw;
    const int l    = threadIdx.x & 63;
    const int g    = l >> 3;                  // group 0..7
    const int ln   = l & 7;                   // lane-in-group; dims ln*8..ln*8+7

    __shared__ float s_m[2][2];               // per-row per-half max
    __shared__ float s_s[2][2];               // per-row per-half expsum
    __shared__ __align__(16) float s_part[2][64]; // half-1 partial out

    const h16* Kb = Kh + ((size_t)b * Nc) * Kc;
    const h16* Vb = Vh + ((size_t)b * Nc) * Kc;

    // Q fragment (16B at dim ln*8); identical across the 8 groups -> broadcast.
    h16x8 qv = *(const h16x8*)(Qh + (((size_t)b * Mc + row) << 6) + ln * 8);

    // This wave's 8 edges per group: e = half*64 + p*8 + g.
    const int* crow = cols + row * Rc + half * 64;
    int col8[8];
    #pragma unroll
    for (int p = 0; p < 8; ++p) col8[p] = crow[p * 8 + g];

    // ---- SDDMM: 8-deep K-row gather (8 lanes x 16B = one 128B line/group) ----
    h16x8 kv[8];
    #pragma unroll
    for (int p = 0; p < 8; ++p)
        kv[p] = *(const h16x8*)(Kb + (((unsigned)col8[p]) << 6) + ln * 8);

    float lg[8];
    #pragma unroll
    for (int p = 0; p < 8; ++p) {
        float acc = 0.f;
        #pragma unroll
        for (int j = 0; j < 4; ++j) {
            h16x2 qj = { qv[2 * j], qv[2 * j + 1] };
            h16x2 kj = { kv[p][2 * j], kv[p][2 * j + 1] };
#if defined(__has_builtin)
#if __has_builtin(__builtin_amdgcn_fdot2)
            acc = __builtin_amdgcn_fdot2(qj, kj, acc, false);
#else
            acc += (float)qj.x * (float)kj.x + (float)qj.y * (float)kj.y;
#endif
#else
            acc += (float)qj.x * (float)kj.x + (float)qj.y * (float)kj.y;
#endif
        }
        acc += __shfl_xor(acc, 1, 64);
        acc += __shfl_xor(acc, 2, 64);
        acc += __shfl_xor(acc, 4, 64);
        lg[p] = acc;                 // logit of edge half*64+p*8+g (all 8 lanes)
    }

    // ---- V gathers: issue now, drain at the barrier (latency hidden by TLP) ----
    h16x8 vv[8];
    #pragma unroll
    for (int p = 0; p < 8; ++p)
        vv[p] = *(const h16x8*)(Vb + (((unsigned)col8[p]) << 6) + ln * 8);

    // ---- softmax: local (64-edge) max, cross-wave exchange, exp, sum ----
    float m = lg[0];
    #pragma unroll
    for (int p = 1; p < 8; ++p) m = fmaxf(m, lg[p]);
    m = fmaxf(m, __shfl_xor(m, 8, 64));
    m = fmaxf(m, __shfl_xor(m, 16, 64));
    m = fmaxf(m, __shfl_xor(m, 32, 64));
    if (l == 0) s_m[rw][half] = m;
    __syncthreads();
    m = fmaxf(s_m[rw][0], s_m[rw][1]);

    float s = 0.f;
    #pragma unroll
    for (int p = 0; p < 8; ++p) { lg[p] = __expf(lg[p] - m); s += lg[p]; }
    s += __shfl_xor(s, 8, 64);
    s += __shfl_xor(s, 16, 64);
    s += __shfl_xor(s, 32, 64);
    if (l == 0) s_s[rw][half] = s;

    // ---- SPMM over this wave's 64 edges ----
    float acc8[8] = {0.f, 0.f, 0.f, 0.f, 0.f, 0.f, 0.f, 0.f};
    #pragma unroll
    for (int p = 0; p < 8; ++p) {
        const float wp = lg[p];
        #pragma unroll
        for (int j = 0; j < 8; ++j)
            acc8[j] = fmaf((float)vv[p][j], wp, acc8[j]);   // v_fma_mix
    }
    // cross-group butterfly: every lane gets the half-row sum for its dims
    #pragma unroll
    for (int j = 0; j < 8; ++j) {
        acc8[j] += __shfl_xor(acc8[j], 8, 64);
        acc8[j] += __shfl_xor(acc8[j], 16, 64);
        acc8[j] += __shfl_xor(acc8[j], 32, 64);
    }

    // half-1 publishes its partial (8 lanes x 32B, conflict-free)
    if (half == 1 && g == 0) {
        *(f32x4*)&s_part[rw][ln * 8]     = f32x4{acc8[0], acc8[1], acc8[2], acc8[3]};
        *(f32x4*)&s_part[rw][ln * 8 + 4] = f32x4{acc8[4], acc8[5], acc8[6], acc8[7]};
    }
    __syncthreads();

    if (half == 0 && g == 0) {
        const float inv = 1.0f / (s_s[rw][0] + s_s[rw][1]);
        const float* pp = &s_part[rw][ln * 8];
        float* orow = out + (((size_t)b * Mc + row) << 6) + ln * 8;
        f32x4 o0 = { (acc8[0] + pp[0]) * inv, (acc8[1] + pp[1]) * inv,
                     (acc8[2] + pp[2]) * inv, (acc8[3] + pp[3]) * inv };
        f32x4 o1 = { (acc8[4] + pp[4]) * inv, (acc8[5] + pp[5]) * inv,
                     (acc8[6] + pp[6]) * inv, (acc8[7] + pp[7]) * inv };
        __builtin_nontemporal_store(o0, (f32x4*)orow);
        __builtin_nontemporal_store(o1, (f32x4*)orow + 1);
    }
}

extern "C" void kernel_launch(void* const* d_in, const int* in_sizes, int n_in,
                              void* d_out, int out_size, void* d_ws, size_t ws_size,
                              hipStream_t stream) {
    // inputs: 0 row_indices, 1 row_offsets, 2 column_indices, 3 q3d, 4 k3d, 5 v3d, 6 values
    const int*   cols = (const int*)d_in[2];
    const float* Qm   = (const float*)d_in[3];
    const float* Km   = (const float*)d_in[4];
    const float* Vm   = (const float*)d_in[5];
    float* out = (float*)d_out;

    h16* Kh = (h16*)d_ws;
    h16* Vh = Kh + (size_t)Bc * Nc * Kc;
    h16* Qh = Vh + (size_t)Bc * Nc * Kc;   // 3 x 4.19 MB = 12.6 MB in d_ws

    cvt_fp16<<<dim3(Bc * 3 * 256), dim3(256), 0, stream>>>(
        (const f32x4*)Km, (const f32x4*)Vm, (const f32x4*)Qm,
        (h16x4*)Kh, (h16x4*)Vh, (h16x4*)Qh);

    sattn_kernel<<<dim3(Bc * Mc / 2), dim3(256), 0, stream>>>(cols, Qh, Kh, Vh, out);
}

// Round 4
// 142.332 us; speedup vs baseline: 1.0825x; 1.0167x over previous
//
#include <hip/hip_runtime.h>

// SparseAttention: B=8, M=N=4096, K=64, R=128 nnz/row (uniform CSR).
// Model (fits R3/R4/R5): random-gather latency*MLP bound; rate =
// lines_in_flight_per_CU * 128B / ~550cy.  R5: 52% occ x 8 lines = 59us,
// VGPR=40 shows compiler re-serialized V loads under the (256,6) cap.
// R6: same 2-waves-per-row shape, but (256,4) cap=128 so all 16 gathers
//     (8 K + 8 V) stay in flight per wave; contiguous per-group cols
//     loaded as two int4 broadcasts.  Target ~256-320 lines/CU.
#define Bc 8
#define Mc 4096
#define Nc 4096
#define Kc 64
#define Rc 128

typedef _Float16 h16;
typedef h16 h16x2 __attribute__((ext_vector_type(2)));
typedef h16 h16x4 __attribute__((ext_vector_type(4)));
typedef h16 h16x8 __attribute__((ext_vector_type(8)));
typedef float f32x4 __attribute__((ext_vector_type(4)));
typedef int   i32x4 __attribute__((ext_vector_type(4)));

// fp32 -> fp16 staging for K, V, Q.  XCD-aware: batch b converted by blocks
// with blockIdx&7 == b (same XCD that sattn's batch-b gathers run on).
__global__ __launch_bounds__(256) void cvt_fp16(
    const f32x4* __restrict__ K4, const f32x4* __restrict__ V4,
    const f32x4* __restrict__ Q4,
    h16x4* __restrict__ Kh4, h16x4* __restrict__ Vh4, h16x4* __restrict__ Qh4)
{
    const int nb4   = Nc * Kc / 4;          // 65536 f32x4 per tensor per batch
    const int b     = blockIdx.x & 7;       // XCD == batch
    const int chunk = blockIdx.x >> 3;      // 0..767
    const int tsel  = chunk >> 8;           // 0:K 1:V 2:Q (256 blocks each)
    const int idx   = b * nb4 + ((chunk & 255) << 8) + threadIdx.x;
    const f32x4* src = (tsel == 0) ? K4 : (tsel == 1) ? V4 : Q4;
    h16x4*       dst = (tsel == 0) ? Kh4 : (tsel == 1) ? Vh4 : Qh4;
    f32x4 v = __builtin_nontemporal_load(&src[idx]);
    h16x4 o = { (h16)v.x, (h16)v.y, (h16)v.z, (h16)v.w };
    dst[idx] = o;
}

__global__ __launch_bounds__(256, 4) void sattn_kernel(
    const int* __restrict__ cols,    // [M*R], sorted within row
    const h16* __restrict__ Qh,      // [B,M,K] fp16 (staged)
    const h16* __restrict__ Kh,      // [B,N,K] fp16 (staged)
    const h16* __restrict__ Vh,      // [B,N,K] fp16 (staged)
    float* __restrict__ out)         // [B,M,K] fp32
{
    const int b    = blockIdx.x & 7;          // XCD swizzle: one batch per XCD L2
    const int rb   = blockIdx.x >> 3;         // row-pair index within batch
    const int w    = threadIdx.x >> 6;        // wave 0..3
    const int rw   = w >> 1;                  // row-in-block 0/1
    const int half = w & 1;                   // which 64 of the row's 128 edges
    const int row  = rb * 2 + rw;
    const int l    = threadIdx.x & 63;
    const int g    = l >> 3;                  // group 0..7
    const int ln   = l & 7;                   // lane-in-group; dims ln*8..ln*8+7

    __shared__ float s_m[2][2];               // per-row per-half max
    __shared__ float s_s[2][2];               // per-row per-half expsum
    __shared__ __align__(16) float s_part[2][64]; // half-1 partial out

    const h16* Kb = Kh + ((size_t)b * Nc) * Kc;
    const h16* Vb = Vh + ((size_t)b * Nc) * Kc;

    // Q fragment (16B at dim ln*8); identical across the 8 groups -> broadcast.
    h16x8 qv = *(const h16x8*)(Qh + (((size_t)b * Mc + row) << 6) + ln * 8);

    // This group's 8 CONTIGUOUS edges: e = half*64 + g*8 + p.
    // Two int4 loads, same 32B for all 8 lanes of the group -> L1 broadcast.
    const int* crow = cols + row * Rc + half * 64 + g * 8;
    i32x4 c0 = *(const i32x4*)crow;
    i32x4 c1 = *(const i32x4*)(crow + 4);
    int col8[8] = { c0[0], c0[1], c0[2], c0[3], c1[0], c1[1], c1[2], c1[3] };

    // ---- Issue ALL 16 gathers back-to-back: 8 K then 8 V.  Consuming K at
    //      vmcnt(8) keeps the V stream in flight under the SDDMM. ----
    h16x8 kv[8];
    #pragma unroll
    for (int p = 0; p < 8; ++p)
        kv[p] = *(const h16x8*)(Kb + (((unsigned)col8[p]) << 6) + ln * 8);
    h16x8 vv[8];
    #pragma unroll
    for (int p = 0; p < 8; ++p)
        vv[p] = *(const h16x8*)(Vb + (((unsigned)col8[p]) << 6) + ln * 8);

    // ---- SDDMM dots (fp16 fdot2) + 8-lane butterfly ----
    float lg[8];
    #pragma unroll
    for (int p = 0; p < 8; ++p) {
        float acc = 0.f;
        #pragma unroll
        for (int j = 0; j < 4; ++j) {
            h16x2 qj = { qv[2 * j], qv[2 * j + 1] };
            h16x2 kj = { kv[p][2 * j], kv[p][2 * j + 1] };
#if defined(__has_builtin)
#if __has_builtin(__builtin_amdgcn_fdot2)
            acc = __builtin_amdgcn_fdot2(qj, kj, acc, false);
#else
            acc += (float)qj.x * (float)kj.x + (float)qj.y * (float)kj.y;
#endif
#else
            acc += (float)qj.x * (float)kj.x + (float)qj.y * (float)kj.y;
#endif
        }
        acc += __shfl_xor(acc, 1, 64);
        acc += __shfl_xor(acc, 2, 64);
        acc += __shfl_xor(acc, 4, 64);
        lg[p] = acc;                 // logit of edge half*64+g*8+p (all 8 lanes)
    }

    // ---- softmax: local (64-edge) max, cross-wave exchange, exp, sum ----
    float m = lg[0];
    #pragma unroll
    for (int p = 1; p < 8; ++p) m = fmaxf(m, lg[p]);
    m = fmaxf(m, __shfl_xor(m, 8, 64));
    m = fmaxf(m, __shfl_xor(m, 16, 64));
    m = fmaxf(m, __shfl_xor(m, 32, 64));
    if (l == 0) s_m[rw][half] = m;
    __syncthreads();
    m = fmaxf(s_m[rw][0], s_m[rw][1]);

    float s = 0.f;
    #pragma unroll
    for (int p = 0; p < 8; ++p) { lg[p] = __expf(lg[p] - m); s += lg[p]; }
    s += __shfl_xor(s, 8, 64);
    s += __shfl_xor(s, 16, 64);
    s += __shfl_xor(s, 32, 64);
    if (l == 0) s_s[rw][half] = s;

    // ---- SPMM over this wave's 64 edges (V already in registers) ----
    float acc8[8] = {0.f, 0.f, 0.f, 0.f, 0.f, 0.f, 0.f, 0.f};
    #pragma unroll
    for (int p = 0; p < 8; ++p) {
        const float wp = lg[p];
        #pragma unroll
        for (int j = 0; j < 8; ++j)
            acc8[j] = fmaf((float)vv[p][j], wp, acc8[j]);   // v_fma_mix
    }
    // cross-group butterfly: every lane gets the half-row sum for its dims
    #pragma unroll
    for (int j = 0; j < 8; ++j) {
        acc8[j] += __shfl_xor(acc8[j], 8, 64);
        acc8[j] += __shfl_xor(acc8[j], 16, 64);
        acc8[j] += __shfl_xor(acc8[j], 32, 64);
    }

    // half-1 publishes its partial (8 lanes x 32B, conflict-free)
    if (half == 1 && g == 0) {
        *(f32x4*)&s_part[rw][ln * 8]     = f32x4{acc8[0], acc8[1], acc8[2], acc8[3]};
        *(f32x4*)&s_part[rw][ln * 8 + 4] = f32x4{acc8[4], acc8[5], acc8[6], acc8[7]};
    }
    __syncthreads();

    if (half == 0 && g == 0) {
        const float inv = 1.0f / (s_s[rw][0] + s_s[rw][1]);
        const float* pp = &s_part[rw][ln * 8];
        float* orow = out + (((size_t)b * Mc + row) << 6) + ln * 8;
        f32x4 o0 = { (acc8[0] + pp[0]) * inv, (acc8[1] + pp[1]) * inv,
                     (acc8[2] + pp[2]) * inv, (acc8[3] + pp[3]) * inv };
        f32x4 o1 = { (acc8[4] + pp[4]) * inv, (acc8[5] + pp[5]) * inv,
                     (acc8[6] + pp[6]) * inv, (acc8[7] + pp[7]) * inv };
        __builtin_nontemporal_store(o0, (f32x4*)orow);
        __builtin_nontemporal_store(o1, (f32x4*)orow + 1);
    }
}

extern "C" void kernel_launch(void* const* d_in, const int* in_sizes, int n_in,
                              void* d_out, int out_size, void* d_ws, size_t ws_size,
                              hipStream_t stream) {
    // inputs: 0 row_indices, 1 row_offsets, 2 column_indices, 3 q3d, 4 k3d, 5 v3d, 6 values
    const int*   cols = (const int*)d_in[2];
    const float* Qm   = (const float*)d_in[3];
    const float* Km   = (const float*)d_in[4];
    const float* Vm   = (const float*)d_in[5];
    float* out = (float*)d_out;

    h16* Kh = (h16*)d_ws;
    h16* Vh = Kh + (size_t)Bc * Nc * Kc;
    h16* Qh = Vh + (size_t)Bc * Nc * Kc;   // 3 x 4.19 MB = 12.6 MB in d_ws

    cvt_fp16<<<dim3(Bc * 3 * 256), dim3(256), 0, stream>>>(
        (const f32x4*)Km, (const f32x4*)Vm, (const f32x4*)Qm,
        (h16x4*)Kh, (h16x4*)Vh, (h16x4*)Qh);

    sattn_kernel<<<dim3(Bc * Mc / 2), dim3(256), 0, stream>>>(cols, Qh, Kh, Vh, out);
}

// Round 5
// 138.526 us; speedup vs baseline: 1.1123x; 1.0275x over previous
//
#include <hip/hip_runtime.h>

// SparseAttention: B=8, M=N=4096, K=64, R=128 nnz/row (uniform CSR).
// Model: random-gather latency*MLP bound + VALU/DS issue co-bottleneck
// (R6: VALUBusy 67%, VGPR=40 -> compiler re-serialized the 16 gathers).
// R7: (a) sched_barrier(0) after issuing all 16 gathers pins them in
//     flight (forces ~100 VGPR live); (b) DPP-based reductions replace
//     ds_swizzle shuffles for masks 1/2/4 (quad_perm + row_half_mirror)
//     and mask 8 (row_ror:8); masks 16/32 stay shfl_xor.
#define Bc 8
#define Mc 4096
#define Nc 4096
#define Kc 64
#define Rc 128

typedef _Float16 h16;
typedef h16 h16x2 __attribute__((ext_vector_type(2)));
typedef h16 h16x4 __attribute__((ext_vector_type(4)));
typedef h16 h16x8 __attribute__((ext_vector_type(8)));
typedef float f32x4 __attribute__((ext_vector_type(4)));
typedef int   i32x4 __attribute__((ext_vector_type(4)));

// DPP cross-lane reduce helpers (VALU, no DS pipe, ~2cy vs ~30cy ds_swizzle).
// XOR1 = quad_perm[1,0,3,2]=0xB1, XOR2 = quad_perm[2,3,0,1]=0x4E,
// MIR8 = row_half_mirror=0x141 (== xor4 once each quad is uniform),
// ROR8 = row_ror:8=0x128 (exact xor8 within a 16-lane row).
template<int CTRL>
__device__ __forceinline__ float dpp_badd(float x) {
    union { float f; int i; } u, r;
    u.f = x;
    r.i = __builtin_amdgcn_update_dpp(0, u.i, CTRL, 0xF, 0xF, true);
    return x + r.f;
}
template<int CTRL>
__device__ __forceinline__ float dpp_bmax(float x) {
    union { float f; int i; } u, r;
    u.f = x;
    r.i = __builtin_amdgcn_update_dpp(0, u.i, CTRL, 0xF, 0xF, true);
    return fmaxf(x, r.f);
}

// fp32 -> fp16 staging for K, V, Q.  XCD-aware: batch b converted by blocks
// with blockIdx&7 == b (same XCD that sattn's batch-b gathers run on).
__global__ __launch_bounds__(256) void cvt_fp16(
    const f32x4* __restrict__ K4, const f32x4* __restrict__ V4,
    const f32x4* __restrict__ Q4,
    h16x4* __restrict__ Kh4, h16x4* __restrict__ Vh4, h16x4* __restrict__ Qh4)
{
    const int nb4   = Nc * Kc / 4;          // 65536 f32x4 per tensor per batch
    const int b     = blockIdx.x & 7;       // XCD == batch
    const int chunk = blockIdx.x >> 3;      // 0..767
    const int tsel  = chunk >> 8;           // 0:K 1:V 2:Q (256 blocks each)
    const int idx   = b * nb4 + ((chunk & 255) << 8) + threadIdx.x;
    const f32x4* src = (tsel == 0) ? K4 : (tsel == 1) ? V4 : Q4;
    h16x4*       dst = (tsel == 0) ? Kh4 : (tsel == 1) ? Vh4 : Qh4;
    f32x4 v = __builtin_nontemporal_load(&src[idx]);
    h16x4 o = { (h16)v.x, (h16)v.y, (h16)v.z, (h16)v.w };
    dst[idx] = o;
}

__global__ __launch_bounds__(256, 4) void sattn_kernel(
    const int* __restrict__ cols,    // [M*R], sorted within row
    const h16* __restrict__ Qh,      // [B,M,K] fp16 (staged)
    const h16* __restrict__ Kh,      // [B,N,K] fp16 (staged)
    const h16* __restrict__ Vh,      // [B,N,K] fp16 (staged)
    float* __restrict__ out)         // [B,M,K] fp32
{
    const int b    = blockIdx.x & 7;          // XCD swizzle: one batch per XCD L2
    const int rb   = blockIdx.x >> 3;         // row-pair index within batch
    const int w    = threadIdx.x >> 6;        // wave 0..3
    const int rw   = w >> 1;                  // row-in-block 0/1
    const int half = w & 1;                   // which 64 of the row's 128 edges
    const int row  = rb * 2 + rw;
    const int l    = threadIdx.x & 63;
    const int g    = l >> 3;                  // group 0..7
    const int ln   = l & 7;                   // lane-in-group; dims ln*8..ln*8+7

    __shared__ float s_m[2][2];               // per-row per-half max
    __shared__ float s_s[2][2];               // per-row per-half expsum
    __shared__ __align__(16) float s_part[2][64]; // half-1 partial out

    const h16* Kb = Kh + ((size_t)b * Nc) * Kc;
    const h16* Vb = Vh + ((size_t)b * Nc) * Kc;

    // Q fragment (16B at dim ln*8); identical across the 8 groups -> broadcast.
    h16x8 qv = *(const h16x8*)(Qh + (((size_t)b * Mc + row) << 6) + ln * 8);

    // This group's 8 CONTIGUOUS edges: e = half*64 + g*8 + p.
    // Two int4 loads, same 32B for all 8 lanes of the group -> L1 broadcast.
    const int* crow = cols + row * Rc + half * 64 + g * 8;
    i32x4 c0 = *(const i32x4*)crow;
    i32x4 c1 = *(const i32x4*)(crow + 4);
    int col8[8] = { c0[0], c0[1], c0[2], c0[3], c1[0], c1[1], c1[2], c1[3] };

    // ---- Issue ALL 16 gathers; sched_barrier(0) pins them in flight
    //      (scheduler cannot sink loads below it -> 16-deep MLP, ~100 VGPR).
    h16x8 kv[8];
    #pragma unroll
    for (int p = 0; p < 8; ++p)
        kv[p] = *(const h16x8*)(Kb + (((unsigned)col8[p]) << 6) + ln * 8);
    h16x8 vv[8];
    #pragma unroll
    for (int p = 0; p < 8; ++p)
        vv[p] = *(const h16x8*)(Vb + (((unsigned)col8[p]) << 6) + ln * 8);
    __builtin_amdgcn_sched_barrier(0);

    // ---- SDDMM dots (fp16 fdot2) + DPP group reduce (masks 1,2,4) ----
    float lg[8];
    #pragma unroll
    for (int p = 0; p < 8; ++p) {
        float acc = 0.f;
        #pragma unroll
        for (int j = 0; j < 4; ++j) {
            h16x2 qj = { qv[2 * j], qv[2 * j + 1] };
            h16x2 kj = { kv[p][2 * j], kv[p][2 * j + 1] };
#if defined(__has_builtin)
#if __has_builtin(__builtin_amdgcn_fdot2)
            acc = __builtin_amdgcn_fdot2(qj, kj, acc, false);
#else
            acc += (float)qj.x * (float)kj.x + (float)qj.y * (float)kj.y;
#endif
#else
            acc += (float)qj.x * (float)kj.x + (float)qj.y * (float)kj.y;
#endif
        }
        acc = dpp_badd<0xB1>(acc);    // xor1
        acc = dpp_badd<0x4E>(acc);    // xor2
        acc = dpp_badd<0x141>(acc);   // xor4 (row_half_mirror, quad-uniform)
        lg[p] = acc;                  // logit of edge half*64+g*8+p (all 8 lanes)
    }

    // ---- softmax: local (64-edge) max, cross-wave exchange, exp, sum ----
    float m = lg[0];
    #pragma unroll
    for (int p = 1; p < 8; ++p) m = fmaxf(m, lg[p]);
    m = dpp_bmax<0x128>(m);                    // xor8 (row_ror:8)
    m = fmaxf(m, __shfl_xor(m, 16, 64));
    m = fmaxf(m, __shfl_xor(m, 32, 64));
    if (l == 0) s_m[rw][half] = m;
    __syncthreads();
    m = fmaxf(s_m[rw][0], s_m[rw][1]);

    float s = 0.f;
    #pragma unroll
    for (int p = 0; p < 8; ++p) { lg[p] = __expf(lg[p] - m); s += lg[p]; }
    s = dpp_badd<0x128>(s);                    // xor8
    s += __shfl_xor(s, 16, 64);
    s += __shfl_xor(s, 32, 64);
    if (l == 0) s_s[rw][half] = s;

    // ---- SPMM over this wave's 64 edges (V already in registers) ----
    float acc8[8] = {0.f, 0.f, 0.f, 0.f, 0.f, 0.f, 0.f, 0.f};
    #pragma unroll
    for (int p = 0; p < 8; ++p) {
        const float wp = lg[p];
        #pragma unroll
        for (int j = 0; j < 8; ++j)
            acc8[j] = fmaf((float)vv[p][j], wp, acc8[j]);   // v_fma_mix
    }
    // cross-group reduce: DPP xor8, then shfl 16/32
    #pragma unroll
    for (int j = 0; j < 8; ++j) {
        acc8[j] = dpp_badd<0x128>(acc8[j]);
        acc8[j] += __shfl_xor(acc8[j], 16, 64);
        acc8[j] += __shfl_xor(acc8[j], 32, 64);
    }

    // half-1 publishes its partial (8 lanes x 32B, conflict-free)
    if (half == 1 && g == 0) {
        *(f32x4*)&s_part[rw][ln * 8]     = f32x4{acc8[0], acc8[1], acc8[2], acc8[3]};
        *(f32x4*)&s_part[rw][ln * 8 + 4] = f32x4{acc8[4], acc8[5], acc8[6], acc8[7]};
    }
    __syncthreads();

    if (half == 0 && g == 0) {
        const float inv = 1.0f / (s_s[rw][0] + s_s[rw][1]);
        const float* pp = &s_part[rw][ln * 8];
        float* orow = out + (((size_t)b * Mc + row) << 6) + ln * 8;
        f32x4 o0 = { (acc8[0] + pp[0]) * inv, (acc8[1] + pp[1]) * inv,
                     (acc8[2] + pp[2]) * inv, (acc8[3] + pp[3]) * inv };
        f32x4 o1 = { (acc8[4] + pp[4]) * inv, (acc8[5] + pp[5]) * inv,
                     (acc8[6] + pp[6]) * inv, (acc8[7] + pp[7]) * inv };
        __builtin_nontemporal_store(o0, (f32x4*)orow);
        __builtin_nontemporal_store(o1, (f32x4*)orow + 1);
    }
}

extern "C" void kernel_launch(void* const* d_in, const int* in_sizes, int n_in,
                              void* d_out, int out_size, void* d_ws, size_t ws_size,
                              hipStream_t stream) {
    // inputs: 0 row_indices, 1 row_offsets, 2 column_indices, 3 q3d, 4 k3d, 5 v3d, 6 values
    const int*   cols = (const int*)d_in[2];
    const float* Qm   = (const float*)d_in[3];
    const float* Km   = (const float*)d_in[4];
    const float* Vm   = (const float*)d_in[5];
    float* out = (float*)d_out;

    h16* Kh = (h16*)d_ws;
    h16* Vh = Kh + (size_t)Bc * Nc * Kc;
    h16* Qh = Vh + (size_t)Bc * Nc * Kc;   // 3 x 4.19 MB = 12.6 MB in d_ws

    cvt_fp16<<<dim3(Bc * 3 * 256), dim3(256), 0, stream>>>(
        (const f32x4*)Km, (const f32x4*)Vm, (const f32x4*)Qm,
        (h16x4*)Kh, (h16x4*)Vh, (h16x4*)Qh);

    sattn_kernel<<<dim3(Bc * Mc / 2), dim3(256), 0, stream>>>(cols, Qh, Kh, Vh, out);
}

// Round 7
// 138.002 us; speedup vs baseline: 1.1165x; 1.0038x over previous
//
#include <hip/hip_runtime.h>

// SparseAttention: B=8, M=N=4096, K=64, R=128 nnz/row (uniform CSR).
// R5-R7 all ~54.5us: effective gather rate 19.6 TB/s (8 lines/cy/XCD, 57% of
// streaming L2).  Compiler re-serialized every register-level attempt at deep
// MLP (VGPR stuck at 40-44 despite (256,4) cap and sched_barrier).
// R8 (resubmit; round-6 run died to container flake before executing):
//     inline-asm gather clause.  16 volatile global_load_dwordx4 (SGPR base +
//     32b voffset) CANNOT be re-serialized; consumption gated by explicit
//     s_waitcnt vmcnt(8)/vmcnt(0) + sched_barrier(0) (rule-18 discipline).
//     "=&v" early-clobber so load dests never alias later asm operands
//     (async register write: dest is garbage until vmcnt drains).
//     Compiler-visible loads (cols, Q) are consumed before the clause; V loads
//     stay in flight across __syncthreads (never-drain), waited before SPMM.
// Discriminates H1 (latency*MLP bound -> ~35-42us) vs H2 (L2 random-line
// ceiling -> flat 54us = roofline).
#define Bc 8
#define Mc 4096
#define Nc 4096
#define Kc 64
#define Rc 128

typedef _Float16 h16;
typedef h16 h16x2 __attribute__((ext_vector_type(2)));
typedef h16 h16x4 __attribute__((ext_vector_type(4)));
typedef h16 h16x8 __attribute__((ext_vector_type(8)));
typedef float f32x4 __attribute__((ext_vector_type(4)));
typedef int   i32x4 __attribute__((ext_vector_type(4)));

// DPP cross-lane reduce helpers (VALU, no DS pipe).
// XOR1 = quad_perm[1,0,3,2]=0xB1, XOR2 = quad_perm[2,3,0,1]=0x4E,
// MIR  = row_half_mirror=0x141 (== xor4 once each quad is uniform),
// ROR8 = row_ror:8=0x128 (exact xor8 within a 16-lane row).
template<int CTRL>
__device__ __forceinline__ float dpp_badd(float x) {
    union { float f; int i; } u, r;
    u.f = x;
    r.i = __builtin_amdgcn_update_dpp(0, u.i, CTRL, 0xF, 0xF, true);
    return x + r.f;
}
template<int CTRL>
__device__ __forceinline__ float dpp_bmax(float x) {
    union { float f; int i; } u, r;
    u.f = x;
    r.i = __builtin_amdgcn_update_dpp(0, u.i, CTRL, 0xF, 0xF, true);
    return fmaxf(x, r.f);
}

// fp32 -> fp16 staging for K, V, Q.  XCD-aware: batch b converted by blocks
// with blockIdx&7 == b (same XCD that sattn's batch-b gathers run on).
__global__ __launch_bounds__(256) void cvt_fp16(
    const f32x4* __restrict__ K4, const f32x4* __restrict__ V4,
    const f32x4* __restrict__ Q4,
    h16x4* __restrict__ Kh4, h16x4* __restrict__ Vh4, h16x4* __restrict__ Qh4)
{
    const int nb4   = Nc * Kc / 4;          // 65536 f32x4 per tensor per batch
    const int b     = blockIdx.x & 7;       // XCD == batch
    const int chunk = blockIdx.x >> 3;      // 0..767
    const int tsel  = chunk >> 8;           // 0:K 1:V 2:Q (256 blocks each)
    const int idx   = b * nb4 + ((chunk & 255) << 8) + threadIdx.x;
    const f32x4* src = (tsel == 0) ? K4 : (tsel == 1) ? V4 : Q4;
    h16x4*       dst = (tsel == 0) ? Kh4 : (tsel == 1) ? Vh4 : Qh4;
    f32x4 v = __builtin_nontemporal_load(&src[idx]);
    h16x4 o = { (h16)v.x, (h16)v.y, (h16)v.z, (h16)v.w };
    dst[idx] = o;
}

__global__ __launch_bounds__(256, 4) void sattn_kernel(
    const int* __restrict__ cols,    // [M*R], sorted within row
    const h16* __restrict__ Qh,      // [B,M,K] fp16 (staged)
    const h16* __restrict__ Kh,      // [B,N,K] fp16 (staged)
    const h16* __restrict__ Vh,      // [B,N,K] fp16 (staged)
    float* __restrict__ out)         // [B,M,K] fp32
{
    const int b    = blockIdx.x & 7;          // XCD swizzle: one batch per XCD L2
    const int rb   = blockIdx.x >> 3;         // row-pair index within batch
    const int w    = threadIdx.x >> 6;        // wave 0..3
    const int rw   = w >> 1;                  // row-in-block 0/1
    const int half = w & 1;                   // which 64 of the row's 128 edges
    const int row  = rb * 2 + rw;
    const int l    = threadIdx.x & 63;
    const int g    = l >> 3;                  // group 0..7
    const int ln   = l & 7;                   // lane-in-group; dims ln*8..ln*8+7

    __shared__ float s_m[2][2];               // per-row per-half max
    __shared__ float s_s[2][2];               // per-row per-half expsum
    __shared__ __align__(16) float s_part[2][64]; // half-1 partial out

    const h16* Kb = Kh + ((size_t)b * Nc) * Kc;
    const h16* Vb = Vh + ((size_t)b * Nc) * Kc;

    // ---- compiler-visible loads FIRST (cols, Q), fully consumed before the
    //      asm clause so hipcc's waitcnt insertion can't touch our stream ----
    const int* crow = cols + row * Rc + half * 64 + g * 8;
    i32x4 c0 = *(const i32x4*)crow;
    i32x4 c1 = *(const i32x4*)(crow + 4);
    int col8[8] = { c0[0], c0[1], c0[2], c0[3], c1[0], c1[1], c1[2], c1[3] };

    h16x8 qv = *(const h16x8*)(Qh + (((size_t)b * Mc + row) << 6) + ln * 8);
    // consume qv into qh NOW (forces the compiler's vmcnt wait here)
    h16x2 qh[4];
    #pragma unroll
    for (int j = 0; j < 4; ++j) qh[j] = h16x2{ qv[2 * j], qv[2 * j + 1] };

    // byte offsets for this group's 8 edges: col*128 + ln*16
    int voff[8];
    #pragma unroll
    for (int p = 0; p < 8; ++p) voff[p] = (col8[p] << 7) + ln * 16;

    // ---- the clause: 16 volatile asm gathers, order-pinned in hardware.
    //      "=&v": dest regs are written asynchronously (only valid after
    //      s_waitcnt), so they must never alias any other operand. ----
    h16x8 kv[8], vv[8];
    #pragma unroll
    for (int p = 0; p < 8; ++p)
        asm volatile("global_load_dwordx4 %0, %1, %2"
                     : "=&v"(kv[p]) : "v"(voff[p]), "s"(Kb));
    #pragma unroll
    for (int p = 0; p < 8; ++p)
        asm volatile("global_load_dwordx4 %0, %1, %2"
                     : "=&v"(vv[p]) : "v"(voff[p]), "s"(Vb));
    // K done when only the 8 V loads remain outstanding.
    asm volatile("s_waitcnt vmcnt(8)");
    __builtin_amdgcn_sched_barrier(0);   // rule 18: nothing hoists above this

    // ---- SDDMM dots (fp16 fdot2) + DPP group reduce (xor1,2,4) ----
    float lg[8];
    #pragma unroll
    for (int p = 0; p < 8; ++p) {
        float acc = 0.f;
        #pragma unroll
        for (int j = 0; j < 4; ++j) {
            h16x2 kj = { kv[p][2 * j], kv[p][2 * j + 1] };
#if defined(__has_builtin)
#if __has_builtin(__builtin_amdgcn_fdot2)
            acc = __builtin_amdgcn_fdot2(qh[j], kj, acc, false);
#else
            acc += (float)qh[j].x * (float)kj.x + (float)qh[j].y * (float)kj.y;
#endif
#else
            acc += (float)qh[j].x * (float)kj.x + (float)qh[j].y * (float)kj.y;
#endif
        }
        acc = dpp_badd<0xB1>(acc);    // xor1
        acc = dpp_badd<0x4E>(acc);    // xor2
        acc = dpp_badd<0x141>(acc);   // xor4 (row_half_mirror, quad-uniform)
        lg[p] = acc;                  // logit of edge half*64+g*8+p (all 8 lanes)
    }

    // ---- softmax: local max, cross-wave exchange, exp, sum.
    //      The 8 V loads stay in flight across the barrier (never-drain). ----
    float m = lg[0];
    #pragma unroll
    for (int p = 1; p < 8; ++p) m = fmaxf(m, lg[p]);
    m = dpp_bmax<0x128>(m);                    // xor8 (row_ror:8)
    m = fmaxf(m, __shfl_xor(m, 16, 64));
    m = fmaxf(m, __shfl_xor(m, 32, 64));
    if (l == 0) s_m[rw][half] = m;
    __syncthreads();
    m = fmaxf(s_m[rw][0], s_m[rw][1]);

    float s = 0.f;
    #pragma unroll
    for (int p = 0; p < 8; ++p) { lg[p] = __expf(lg[p] - m); s += lg[p]; }
    s = dpp_badd<0x128>(s);                    // xor8
    s += __shfl_xor(s, 16, 64);
    s += __shfl_xor(s, 32, 64);
    if (l == 0) s_s[rw][half] = s;

    // ---- now (and only now) drain the V stream ----
    asm volatile("s_waitcnt vmcnt(0)");
    __builtin_amdgcn_sched_barrier(0);

    // ---- SPMM over this wave's 64 edges (V in registers) ----
    float acc8[8] = {0.f, 0.f, 0.f, 0.f, 0.f, 0.f, 0.f, 0.f};
    #pragma unroll
    for (int p = 0; p < 8; ++p) {
        const float wp = lg[p];
        #pragma unroll
        for (int j = 0; j < 8; ++j)
            acc8[j] = fmaf((float)vv[p][j], wp, acc8[j]);   // v_fma_mix
    }
    // cross-group reduce: DPP xor8, then shfl 16/32
    #pragma unroll
    for (int j = 0; j < 8; ++j) {
        acc8[j] = dpp_badd<0x128>(acc8[j]);
        acc8[j] += __shfl_xor(acc8[j], 16, 64);
        acc8[j] += __shfl_xor(acc8[j], 32, 64);
    }

    // half-1 publishes its partial (8 lanes x 32B, conflict-free)
    if (half == 1 && g == 0) {
        *(f32x4*)&s_part[rw][ln * 8]     = f32x4{acc8[0], acc8[1], acc8[2], acc8[3]};
        *(f32x4*)&s_part[rw][ln * 8 + 4] = f32x4{acc8[4], acc8[5], acc8[6], acc8[7]};
    }
    __syncthreads();

    if (half == 0 && g == 0) {
        const float inv = 1.0f / (s_s[rw][0] + s_s[rw][1]);
        const float* pp = &s_part[rw][ln * 8];
        float* orow = out + (((size_t)b * Mc + row) << 6) + ln * 8;
        f32x4 o0 = { (acc8[0] + pp[0]) * inv, (acc8[1] + pp[1]) * inv,
                     (acc8[2] + pp[2]) * inv, (acc8[3] + pp[3]) * inv };
        f32x4 o1 = { (acc8[4] + pp[4]) * inv, (acc8[5] + pp[5]) * inv,
                     (acc8[6] + pp[6]) * inv, (acc8[7] + pp[7]) * inv };
        __builtin_nontemporal_store(o0, (f32x4*)orow);
        __builtin_nontemporal_store(o1, (f32x4*)orow + 1);
    }
}

extern "C" void kernel_launch(void* const* d_in, const int* in_sizes, int n_in,
                              void* d_out, int out_size, void* d_ws, size_t ws_size,
                              hipStream_t stream) {
    // inputs: 0 row_indices, 1 row_offsets, 2 column_indices, 3 q3d, 4 k3d, 5 v3d, 6 values
    const int*   cols = (const int*)d_in[2];
    const float* Qm   = (const float*)d_in[3];
    const float* Km   = (const float*)d_in[4];
    const float* Vm   = (const float*)d_in[5];
    float* out = (float*)d_out;

    h16* Kh = (h16*)d_ws;
    h16* Vh = Kh + (size_t)Bc * Nc * Kc;
    h16* Qh = Vh + (size_t)Bc * Nc * Kc;   // 3 x 4.19 MB = 12.6 MB in d_ws

    cvt_fp16<<<dim3(Bc * 3 * 256), dim3(256), 0, stream>>>(
        (const f32x4*)Km, (const f32x4*)Vm, (const f32x4*)Qm,
        (h16x4*)Kh, (h16x4*)Vh, (h16x4*)Qh);

    sattn_kernel<<<dim3(Bc * Mc / 2), dim3(256), 0, stream>>>(cols, Qh, Kh, Vh, out);
}